// Round 2
// baseline (562.903 us; speedup 1.0000x reference)
//
#include <hip/hip_runtime.h>
#include <stdint.h>

// GoalDecoderLSTM: B=131072 indep LSTM decoders, H=64, E=16, SEQ=30. f32 I/O.
// R8: 2-tile ILP. R7 post-mortem: VALU diet cut VALUBusy 64->59% as predicted
// but time was FLAT -> not VALU-throughput-bound; latency/dependency-bound
// (pipes 80% busy, 2.7 waves/SIMD, per-step serial chain barrier->ds_read->
// rel-MFMA->build_x->gate-MFMA x3->exp2 chain->ds_write). Fix: each block now
// runs TWO independent 16-batch tiles (32 batches/block, grid 4096). The two
// tiles' chains interleave within each wave -> latency gaps filled by ILP,
// not occupancy. Weights (48 VGPR of bw + awp + Wse consts) are SHARED
// between tiles; only state duplicates (~+15 persistent VGPR). Barrier count
// per batch-element halves. Wave w==t stores tile t.
// Kept from R7: all-quad rel (no shuffles), lrelu rank-2 fold into k-slots
// 16..18, f32x2-paired nonlinearity, prescaled gate weights (-log2e/+2log2e),
// shared-denominator sigma/tanh (5 exp2 + 2 rcp per element).

#define B_TOT 131072
#define SEQL 30
#define NT 2  // batch tiles per block

typedef _Float16 f16x8 __attribute__((ext_vector_type(8)));
typedef _Float16 f16x2 __attribute__((ext_vector_type(2)));
typedef float f32x4 __attribute__((ext_vector_type(4)));
typedef float f32x2 __attribute__((ext_vector_type(2)));

__device__ __forceinline__ float fexp2(float x) {
#if __has_builtin(__builtin_amdgcn_exp2f)
  return __builtin_amdgcn_exp2f(x);
#else
  return exp2f(x);
#endif
}
__device__ __forceinline__ float frcp(float x) {
#if __has_builtin(__builtin_amdgcn_rcpf)
  return __builtin_amdgcn_rcpf(x);
#else
  return 1.0f / x;
#endif
}

// ws layout (floats): [0:64] M0, [64:128] M1,
// [128..135] Sx0,Sx1,Sy0,Sy1,Sb0,Sb1,C00,C01.
__global__ void setup_consts(const float* __restrict__ Wgoal,
                             const float* __restrict__ bgoal,
                             const float* __restrict__ Wh2p,
                             const float* __restrict__ bh2p,
                             const float* __restrict__ Wabs,
                             const float* __restrict__ babs,
                             float* __restrict__ wsf) {
  const int tid = threadIdx.x;
  const int wv = tid >> 6;
  const int lane = tid & 63;
  if (wv == 0) {
    const int k = lane;
    float s0 = 0.f, s1 = 0.f;
#pragma unroll 8
    for (int jj = 0; jj < 64; ++jj) {
      float wg = Wgoal[jj * 64 + k];
      s0 += wg * Wh2p[128 + jj];
      s1 += wg * Wh2p[320 + jj];
    }
    wsf[k] = s0;
    wsf[64 + k] = s1;
  } else {
    const int i = lane >> 3, sub = lane & 7;
    const int p = i & 1, grp = i >> 1;
    float s = 0.f;
#pragma unroll
    for (int t = 0; t < 8; ++t) {
      int j = sub * 8 + t;
      float wv_ = (grp < 3) ? Wh2p[p * 192 + 64 + j] : Wh2p[p * 192 + 128 + j];
      float av = (grp == 0)   ? Wabs[j * 2 + 0]
                 : (grp == 1) ? Wabs[j * 2 + 1]
                 : (grp == 2) ? babs[j]
                              : bgoal[j];
      s += av * wv_;
    }
    s += __shfl_xor(s, 1, 64);
    s += __shfl_xor(s, 2, 64);
    s += __shfl_xor(s, 4, 64);
    if (sub == 0) {
      if (grp == 2) s += bh2p[p];
      wsf[128 + i] = s;
    }
  }
}

__global__ __launch_bounds__(256, 4) void lstm_mfma(
    const float* __restrict__ tabs, const float* __restrict__ trel,
    const float* __restrict__ h0, const float* __restrict__ c0,
    const float* __restrict__ goals, const float* __restrict__ Wih,
    const float* __restrict__ Whh, const float* __restrict__ bih,
    const float* __restrict__ bhh, const float* __restrict__ Wse,
    const float* __restrict__ bse, const float* __restrict__ Wh2p,
    const float* __restrict__ wsf, float* __restrict__ outp) {
  const int lane = threadIdx.x & 63;
  const int w = threadIdx.x >> 6;  // wave: hidden slice [16w,16w+16)
  const int q = lane >> 4;         // quad
  const int n = lane & 15;         // N-col / batch index (also A-row m)
  const int pm = n & 3;            // replicated rel/goal A-row selector
  const int hs = 16 * w;
  const int bbase = blockIdx.x * (16 * NT);

  // [dbuf(2)][tile(2)][16 rows x stride 72]
  __shared__ __align__(16) _Float16 hbuf[2 * NT * 16 * 72];

  // ---- gate weight B-frags, PRESCALED so accs are exp2-ready (SHARED) ----
  // i,f,o: *-log2e (acc = -gate*log2e); g: *+2log2e (acc = 2g*log2e)
  const float SI = -1.4426950408889634f;
  const float SG = 2.8853900817779268f;
  const float gsc[4] = {SI, SI, SG, SI};
  f16x8 bw[4][3];
#pragma unroll
  for (int g = 0; g < 4; ++g) {
    const int row = g * 64 + hs + n;
    const float sc = gsc[g];
#pragma unroll
    for (int kk = 0; kk < 2; ++kk)
#pragma unroll
      for (int j = 0; j < 8; ++j)
        bw[g][kk][j] = (_Float16)(sc * Whh[row * 64 + kk * 32 + q * 8 + j]);
    // rank-2 fold of the 0.505*u part of lrelu: k-slots 17,18 + f32 bias.
    float bfold = 0.f, m20 = 0.f, m21 = 0.f;
#pragma unroll
    for (int k = 0; k < 16; ++k) {
      float wik = Wih[row * 16 + k];
      bfold += bse[k] * wik;
      m20 += Wse[k * 2 + 0] * wik;
      m21 += Wse[k * 2 + 1] * wik;
    }
    float bias = sc * (bih[row] + bhh[row] + 0.505f * bfold);
#pragma unroll
    for (int j = 0; j < 8; ++j) {
      float v;
      if (q < 2)
        v = sc * Wih[row * 16 + q * 8 + j];  // k=0..15: pairs with 0.495|u|
      else if (q == 2 && j == 0)
        v = bias;  // k=16: pairs with A=1
      else if (q == 2 && j == 1)
        v = sc * 0.505f * m20;  // k=17: pairs with A=rel0
      else if (q == 2 && j == 2)
        v = sc * 0.505f * m21;  // k=18: pairs with A=rel1
      else
        v = 0.f;
      bw[g][2][j] = (_Float16)v;
    }
  }
  // ---- rel projection A-frags, replicated rows m&3<2 (SHARED) ----
  f16x8 awp0, awp1;
#pragma unroll
  for (int j = 0; j < 8; ++j) {
    float v0 = (pm < 2) ? Wh2p[pm * 192 + q * 8 + j] : 0.f;
    float v1 = (pm < 2) ? Wh2p[pm * 192 + 32 + q * 8 + j] : 0.f;
    awp0[j] = (_Float16)v0;
    awp1[j] = (_Float16)v1;
  }
  const float Sx0 = wsf[128], Sx1 = wsf[129];
  const float Sy0 = wsf[130], Sy1 = wsf[131];

  // ---- Wse consts (pre-scaled by 0.495) as pk pairs (SHARED) ----
  f16x2 wsaP[4], wsbP[4], bscP[4];
  const uint32_t xmask = (q < 2) ? 0x7FFF7FFFu : 0xFFFFFFFFu;
#pragma unroll
  for (int jj = 0; jj < 4; ++jj) {
    f16x2 z = f16x2{(_Float16)0.f, (_Float16)0.f};
    if (q < 2) {
      int kx = q * 8 + 2 * jj;
      wsaP[jj] =
          f16x2{(_Float16)(0.495f * Wse[kx * 2 + 0]),
                (_Float16)(0.495f * Wse[kx * 2 + 2])};
      wsbP[jj] =
          f16x2{(_Float16)(0.495f * Wse[kx * 2 + 1]),
                (_Float16)(0.495f * Wse[kx * 2 + 3])};
      bscP[jj] = f16x2{(_Float16)(0.495f * bse[kx]),
                       (_Float16)(0.495f * bse[kx + 1])};
    } else if (q == 2 && jj == 0) {
      wsaP[jj] = f16x2{(_Float16)0.f, (_Float16)1.f};  // t = {1, r0}
      wsbP[jj] = z;
      bscP[jj] = f16x2{(_Float16)1.f, (_Float16)0.f};
    } else if (q == 2 && jj == 1) {
      wsaP[jj] = z;  // t = {r1, 0}
      wsbP[jj] = f16x2{(_Float16)1.f, (_Float16)0.f};
      bscP[jj] = z;
    } else {
      wsaP[jj] = z;
      wsbP[jj] = z;
      bscP[jj] = z;
    }
  }

  auto build_x = [&](float r0f, float r1f) -> f16x8 {
    f16x2 r0h = f16x2{(_Float16)r0f, (_Float16)r0f};
    f16x2 r1h = f16x2{(_Float16)r1f, (_Float16)r1f};
    f16x8 xr;
#pragma unroll
    for (int jj = 0; jj < 4; ++jj) {
      f16x2 t = r0h * wsaP[jj] + (r1h * wsbP[jj] + bscP[jj]);
      uint32_t tu = __builtin_bit_cast(uint32_t, t) & xmask;  // 0.495|u| / raw
      f16x2 lr = __builtin_bit_cast(f16x2, tu);
      xr[2 * jj] = lr[0];
      xr[2 * jj + 1] = lr[1];
    }
    return xr;
  };

  const f32x4 zC = {0.f, 0.f, 0.f, 0.f};

  // ---- per-tile state ----
  f32x4 GaccT[NT];
  float ax[NT], ay[NT], cst[NT][4];
  f16x8 xf[NT];
  {
    // goal-const A-frags shared across tiles; B-frag (goals) per tile.
    f16x8 aM0, aM1;
#pragma unroll
    for (int j = 0; j < 8; ++j) {
      int k = q * 8 + j;
      aM0[j] = (_Float16)((pm < 2) ? wsf[pm * 64 + k] : 0.f);
      aM1[j] = (_Float16)((pm < 2) ? wsf[pm * 64 + 32 + k] : 0.f);
    }
    const float Sb0 = wsf[132] + wsf[134];
    const float Sb1 = wsf[133] + wsf[135];
#pragma unroll
    for (int t = 0; t < NT; ++t) {
      const int bb = bbase + 16 * t;
      f16x8 bg0, bg1;
#pragma unroll
      for (int j = 0; j < 8; ++j) {
        int k = q * 8 + j;
        bg0[j] = (_Float16)goals[(bb + n) * 64 + k];
        bg1[j] = (_Float16)goals[(bb + n) * 64 + 32 + k];
      }
      f32x4 Ga = __builtin_amdgcn_mfma_f32_16x16x32_f16(aM0, bg0, zC, 0, 0, 0);
      Ga = __builtin_amdgcn_mfma_f32_16x16x32_f16(aM1, bg1, Ga, 0, 0, 0);
      Ga[0] += Sb0;
      Ga[1] += Sb1;
      GaccT[t] = Ga;

      ax[t] = tabs[(bb + n) * 2 + 0];
      ay[t] = tabs[(bb + n) * 2 + 1];
#pragma unroll
      for (int r = 0; r < 4; ++r) {
        const int b = bb + 4 * q + r;
        cst[t][r] = c0[b * 64 + hs + n];
        hbuf[t * 1152 + (4 * q + r) * 72 + hs + n] =
            (_Float16)h0[b * 64 + hs + n];
      }
      xf[t] = build_x(trel[(bb + n) * 2 + 0], trel[(bb + n) * 2 + 1]);
    }
  }

  const int ro = n * 72 + q * 8;
  const int wo = (4 * q) * 72 + hs + n;
  const float K2 = 2.8853900817779268f;

  int poff = 0;  // dbuf toggle: 0 <-> 2304
  for (int s = 0; s <= SEQL; ++s) {
    __syncthreads();  // hbuf[poff] holds h_s for all 64 hidden units, both tiles
    f16x8 ah0[NT], ah1[NT];
#pragma unroll
    for (int t = 0; t < NT; ++t) {
      ah0[t] = *(const f16x8*)(hbuf + poff + t * 1152 + ro);
      ah1[t] = *(const f16x8*)(hbuf + poff + t * 1152 + ro + 32);
    }

    if (s > 0) {
      // rel_{s-1}: D[p][batch], regs 0,1 valid on every quad -> lane-local.
      f32x4 pa[NT];
#pragma unroll
      for (int t = 0; t < NT; ++t) {
        f32x4 p = __builtin_amdgcn_mfma_f32_16x16x32_f16(awp0, ah0[t],
                                                         GaccT[t], 0, 0, 0);
        pa[t] = __builtin_amdgcn_mfma_f32_16x16x32_f16(awp1, ah1[t], p,
                                                       0, 0, 0);
      }
#pragma unroll
      for (int t = 0; t < NT; ++t) {
        float u0 = pa[t][0] + fmaf(ax[t], Sx0, ay[t] * Sy0);
        float u1 = pa[t][1] + fmaf(ax[t], Sx1, ay[t] * Sy1);
        ax[t] += u0;
        ay[t] += u1;
        if (w == t && lane < 16) {
          float2 v;
          v.x = u0;
          v.y = u1;
          ((float2*)outp)[(size_t)(s - 1) * B_TOT + bbase + 16 * t + lane] = v;
        }
        xf[t] = build_x(u0, u1);  // u0,u1 lane-local, no shuffle
      }
    }

    if (s < SEQL) {
      f32x4 acc[NT][4];
#pragma unroll
      for (int g = 0; g < 4; ++g)
#pragma unroll
        for (int t = 0; t < NT; ++t) {
          f32x4 a = __builtin_amdgcn_mfma_f32_16x16x32_f16(ah0[t], bw[g][0],
                                                           zC, 0, 0, 0);
          a = __builtin_amdgcn_mfma_f32_16x16x32_f16(ah1[t], bw[g][1], a,
                                                     0, 0, 0);
          a = __builtin_amdgcn_mfma_f32_16x16x32_f16(xf[t], bw[g][2], a,
                                                     0, 0, 0);
          acc[t][g] = a;
        }
#pragma unroll
      for (int t = 0; t < NT; ++t) {
        _Float16* hw = hbuf + (poff ^ 2304) + t * 1152 + wo;
        // accs prescaled: acc0=-i*log2e, acc1=-f*log2e, acc2=2g*log2e,
        // acc3=-o*log2e. Pairwise f32x2 so non-trans ALU goes v_pk_*_f32.
#pragma unroll
        for (int pr = 0; pr < 2; ++pr) {
          const int ra = 2 * pr, rb = 2 * pr + 1;
          f32x2 Av = {fexp2(acc[t][0][ra]), fexp2(acc[t][0][rb])};
          f32x2 Fv = {fexp2(acc[t][1][ra]), fexp2(acc[t][1][rb])};
          f32x2 Bv = {fexp2(acc[t][2][ra]), fexp2(acc[t][2][rb])};
          const f32x2 one = {1.f, 1.f};
          f32x2 t1 = Av + one;
          f32x2 t2 = Bv + one;
          f32x2 t3 = Fv + one;
          f32x2 t4 = Bv - one;
          f32x2 m1 = t1 * t2;
          f32x2 cs = {cst[t][ra], cst[t][rb]};
          f32x2 num = cs * m1 + t4 * t3;
          f32x2 den = m1 * t3;
          f32x2 cc = {num[0] * frcp(den[0]), num[1] * frcp(den[1])};
          cst[t][ra] = cc[0];
          cst[t][rb] = cc[1];
          f32x2 Cv = {fexp2(acc[t][3][ra]), fexp2(acc[t][3][rb])};
          f32x2 k2c = cc * K2;
          f32x2 Dv = {fexp2(k2c[0]), fexp2(k2c[1])};
          f32x2 hd = (Cv + one) * (Dv + one);
          f32x2 hnm = Dv - one;
          hw[72 * ra] = (_Float16)(hnm[0] * frcp(hd[0]));
          hw[72 * rb] = (_Float16)(hnm[1] * frcp(hd[1]));
        }
      }
      poff ^= 2304;
    }
  }
}

extern "C" void kernel_launch(void* const* d_in, const int* in_sizes, int n_in,
                              void* d_out, int out_size, void* d_ws,
                              size_t ws_size, hipStream_t stream) {
  (void)in_sizes; (void)n_in; (void)out_size; (void)ws_size;
  const float* tabs  = (const float*)d_in[0];
  const float* trel  = (const float*)d_in[1];
  const float* h0    = (const float*)d_in[2];
  const float* c0    = (const float*)d_in[3];
  const float* goals = (const float*)d_in[4];
  const float* Wih   = (const float*)d_in[5];
  const float* Whh   = (const float*)d_in[6];
  const float* bih   = (const float*)d_in[7];
  const float* bhh   = (const float*)d_in[8];
  const float* Wse   = (const float*)d_in[9];
  const float* bse   = (const float*)d_in[10];
  const float* Wh2p  = (const float*)d_in[11];
  const float* bh2p  = (const float*)d_in[12];
  const float* Wgoal = (const float*)d_in[13];
  const float* bgoal = (const float*)d_in[14];
  const float* Wabs  = (const float*)d_in[15];
  const float* babs  = (const float*)d_in[16];
  float* wsf = (float*)d_ws;

  setup_consts<<<dim3(1), dim3(128), 0, stream>>>(Wgoal, bgoal, Wh2p, bh2p,
                                                  Wabs, babs, wsf);
  lstm_mfma<<<dim3(B_TOT / (16 * NT)), dim3(256), 0, stream>>>(
      tabs, trel, h0, c0, goals, Wih, Whh, bih, bhh, Wse, bse, Wh2p, wsf,
      (float*)d_out);
}

// Round 3
// 462.585 us; speedup vs baseline: 1.2169x; 1.2169x over previous
//
#include <hip/hip_runtime.h>
#include <stdint.h>

// GoalDecoderLSTM: B=131072 indep LSTM decoders, H=64, E=16, SEQ=30. f32 I/O.
// R9: 2-tile ILP, spill-free. R8 post-mortem: __launch_bounds__(256,4)'s
// 128-reg cap (64 VGPR + 64 AGPR reported) forced ~215 MB/dispatch of scratch
// traffic (FETCH 50->116 MB, WRITE 31->181 MB) yet time only fell to 479us ->
// the 2-tile ILP structure is sound, the register cap was the bug. Also
// explains R6/R7 occupancy 33%: true footprint = VGPR+AGPR ~ 168 regs, i.e.
// 3 waves/SIMD, not 6. Fix: bounds(256,3) -> 168-reg cap (fits est. ~156
// peak), plus slim the per-tile goal accumulator from a live f32x4 C-input
// (8 VGPR) to two scalars added post-MFMA (4 VGPR, zC is C-in).
// Kept from R8: two independent 16-batch tiles per block (grid 4096), shared
// weight frags, g-major gate MFMAs over both tiles, per-tile sequential
// nonlinearity, wave w==t stores tile t.
// Kept from R7: all-quad rel (no shuffles), lrelu rank-2 fold into k-slots
// 16..18, f32x2-paired nonlinearity, prescaled gate weights (-log2e/+2log2e),
// shared-denominator sigma/tanh (5 exp2 + 2 rcp per element).

#define B_TOT 131072
#define SEQL 30
#define NT 2  // batch tiles per block

typedef _Float16 f16x8 __attribute__((ext_vector_type(8)));
typedef _Float16 f16x2 __attribute__((ext_vector_type(2)));
typedef float f32x4 __attribute__((ext_vector_type(4)));
typedef float f32x2 __attribute__((ext_vector_type(2)));

__device__ __forceinline__ float fexp2(float x) {
#if __has_builtin(__builtin_amdgcn_exp2f)
  return __builtin_amdgcn_exp2f(x);
#else
  return exp2f(x);
#endif
}
__device__ __forceinline__ float frcp(float x) {
#if __has_builtin(__builtin_amdgcn_rcpf)
  return __builtin_amdgcn_rcpf(x);
#else
  return 1.0f / x;
#endif
}

// ws layout (floats): [0:64] M0, [64:128] M1,
// [128..135] Sx0,Sx1,Sy0,Sy1,Sb0,Sb1,C00,C01.
__global__ void setup_consts(const float* __restrict__ Wgoal,
                             const float* __restrict__ bgoal,
                             const float* __restrict__ Wh2p,
                             const float* __restrict__ bh2p,
                             const float* __restrict__ Wabs,
                             const float* __restrict__ babs,
                             float* __restrict__ wsf) {
  const int tid = threadIdx.x;
  const int wv = tid >> 6;
  const int lane = tid & 63;
  if (wv == 0) {
    const int k = lane;
    float s0 = 0.f, s1 = 0.f;
#pragma unroll 8
    for (int jj = 0; jj < 64; ++jj) {
      float wg = Wgoal[jj * 64 + k];
      s0 += wg * Wh2p[128 + jj];
      s1 += wg * Wh2p[320 + jj];
    }
    wsf[k] = s0;
    wsf[64 + k] = s1;
  } else {
    const int i = lane >> 3, sub = lane & 7;
    const int p = i & 1, grp = i >> 1;
    float s = 0.f;
#pragma unroll
    for (int t = 0; t < 8; ++t) {
      int j = sub * 8 + t;
      float wv_ = (grp < 3) ? Wh2p[p * 192 + 64 + j] : Wh2p[p * 192 + 128 + j];
      float av = (grp == 0)   ? Wabs[j * 2 + 0]
                 : (grp == 1) ? Wabs[j * 2 + 1]
                 : (grp == 2) ? babs[j]
                              : bgoal[j];
      s += av * wv_;
    }
    s += __shfl_xor(s, 1, 64);
    s += __shfl_xor(s, 2, 64);
    s += __shfl_xor(s, 4, 64);
    if (sub == 0) {
      if (grp == 2) s += bh2p[p];
      wsf[128 + i] = s;
    }
  }
}

__global__ __launch_bounds__(256, 3) void lstm_mfma(
    const float* __restrict__ tabs, const float* __restrict__ trel,
    const float* __restrict__ h0, const float* __restrict__ c0,
    const float* __restrict__ goals, const float* __restrict__ Wih,
    const float* __restrict__ Whh, const float* __restrict__ bih,
    const float* __restrict__ bhh, const float* __restrict__ Wse,
    const float* __restrict__ bse, const float* __restrict__ Wh2p,
    const float* __restrict__ wsf, float* __restrict__ outp) {
  const int lane = threadIdx.x & 63;
  const int w = threadIdx.x >> 6;  // wave: hidden slice [16w,16w+16)
  const int q = lane >> 4;         // quad
  const int n = lane & 15;         // N-col / batch index (also A-row m)
  const int pm = n & 3;            // replicated rel/goal A-row selector
  const int hs = 16 * w;
  const int bbase = blockIdx.x * (16 * NT);

  // [dbuf(2)][tile(2)][16 rows x stride 72]
  __shared__ __align__(16) _Float16 hbuf[2 * NT * 16 * 72];

  // ---- gate weight B-frags, PRESCALED so accs are exp2-ready (SHARED) ----
  // i,f,o: *-log2e (acc = -gate*log2e); g: *+2log2e (acc = 2g*log2e)
  const float SI = -1.4426950408889634f;
  const float SG = 2.8853900817779268f;
  const float gsc[4] = {SI, SI, SG, SI};
  f16x8 bw[4][3];
#pragma unroll
  for (int g = 0; g < 4; ++g) {
    const int row = g * 64 + hs + n;
    const float sc = gsc[g];
#pragma unroll
    for (int kk = 0; kk < 2; ++kk)
#pragma unroll
      for (int j = 0; j < 8; ++j)
        bw[g][kk][j] = (_Float16)(sc * Whh[row * 64 + kk * 32 + q * 8 + j]);
    // rank-2 fold of the 0.505*u part of lrelu: k-slots 17,18 + f32 bias.
    float bfold = 0.f, m20 = 0.f, m21 = 0.f;
#pragma unroll
    for (int k = 0; k < 16; ++k) {
      float wik = Wih[row * 16 + k];
      bfold += bse[k] * wik;
      m20 += Wse[k * 2 + 0] * wik;
      m21 += Wse[k * 2 + 1] * wik;
    }
    float bias = sc * (bih[row] + bhh[row] + 0.505f * bfold);
#pragma unroll
    for (int j = 0; j < 8; ++j) {
      float v;
      if (q < 2)
        v = sc * Wih[row * 16 + q * 8 + j];  // k=0..15: pairs with 0.495|u|
      else if (q == 2 && j == 0)
        v = bias;  // k=16: pairs with A=1
      else if (q == 2 && j == 1)
        v = sc * 0.505f * m20;  // k=17: pairs with A=rel0
      else if (q == 2 && j == 2)
        v = sc * 0.505f * m21;  // k=18: pairs with A=rel1
      else
        v = 0.f;
      bw[g][2][j] = (_Float16)v;
    }
  }
  // ---- rel projection A-frags, replicated rows m&3<2 (SHARED) ----
  f16x8 awp0, awp1;
#pragma unroll
  for (int j = 0; j < 8; ++j) {
    float v0 = (pm < 2) ? Wh2p[pm * 192 + q * 8 + j] : 0.f;
    float v1 = (pm < 2) ? Wh2p[pm * 192 + 32 + q * 8 + j] : 0.f;
    awp0[j] = (_Float16)v0;
    awp1[j] = (_Float16)v1;
  }
  const float Sx0 = wsf[128], Sx1 = wsf[129];
  const float Sy0 = wsf[130], Sy1 = wsf[131];

  // ---- Wse consts (pre-scaled by 0.495) as pk pairs (SHARED) ----
  f16x2 wsaP[4], wsbP[4], bscP[4];
  const uint32_t xmask = (q < 2) ? 0x7FFF7FFFu : 0xFFFFFFFFu;
#pragma unroll
  for (int jj = 0; jj < 4; ++jj) {
    f16x2 z = f16x2{(_Float16)0.f, (_Float16)0.f};
    if (q < 2) {
      int kx = q * 8 + 2 * jj;
      wsaP[jj] =
          f16x2{(_Float16)(0.495f * Wse[kx * 2 + 0]),
                (_Float16)(0.495f * Wse[kx * 2 + 2])};
      wsbP[jj] =
          f16x2{(_Float16)(0.495f * Wse[kx * 2 + 1]),
                (_Float16)(0.495f * Wse[kx * 2 + 3])};
      bscP[jj] = f16x2{(_Float16)(0.495f * bse[kx]),
                       (_Float16)(0.495f * bse[kx + 1])};
    } else if (q == 2 && jj == 0) {
      wsaP[jj] = f16x2{(_Float16)0.f, (_Float16)1.f};  // t = {1, r0}
      wsbP[jj] = z;
      bscP[jj] = f16x2{(_Float16)1.f, (_Float16)0.f};
    } else if (q == 2 && jj == 1) {
      wsaP[jj] = z;  // t = {r1, 0}
      wsbP[jj] = f16x2{(_Float16)1.f, (_Float16)0.f};
      bscP[jj] = z;
    } else {
      wsaP[jj] = z;
      wsbP[jj] = z;
      bscP[jj] = z;
    }
  }

  auto build_x = [&](float r0f, float r1f) -> f16x8 {
    f16x2 r0h = f16x2{(_Float16)r0f, (_Float16)r0f};
    f16x2 r1h = f16x2{(_Float16)r1f, (_Float16)r1f};
    f16x8 xr;
#pragma unroll
    for (int jj = 0; jj < 4; ++jj) {
      f16x2 t = r0h * wsaP[jj] + (r1h * wsbP[jj] + bscP[jj]);
      uint32_t tu = __builtin_bit_cast(uint32_t, t) & xmask;  // 0.495|u| / raw
      f16x2 lr = __builtin_bit_cast(f16x2, tu);
      xr[2 * jj] = lr[0];
      xr[2 * jj + 1] = lr[1];
    }
    return xr;
  };

  const f32x4 zC = {0.f, 0.f, 0.f, 0.f};

  // ---- per-tile state (goal contribution slimmed to 2 scalars/tile) ----
  float Gg0[NT], Gg1[NT];
  float ax[NT], ay[NT], cst[NT][4];
  f16x8 xf[NT];
  {
    // goal-const A-frags shared across tiles; B-frag (goals) per tile.
    f16x8 aM0, aM1;
#pragma unroll
    for (int j = 0; j < 8; ++j) {
      int k = q * 8 + j;
      aM0[j] = (_Float16)((pm < 2) ? wsf[pm * 64 + k] : 0.f);
      aM1[j] = (_Float16)((pm < 2) ? wsf[pm * 64 + 32 + k] : 0.f);
    }
    const float Sb0 = wsf[132] + wsf[134];
    const float Sb1 = wsf[133] + wsf[135];
#pragma unroll
    for (int t = 0; t < NT; ++t) {
      const int bb = bbase + 16 * t;
      f16x8 bg0, bg1;
#pragma unroll
      for (int j = 0; j < 8; ++j) {
        int k = q * 8 + j;
        bg0[j] = (_Float16)goals[(bb + n) * 64 + k];
        bg1[j] = (_Float16)goals[(bb + n) * 64 + 32 + k];
      }
      f32x4 Ga = __builtin_amdgcn_mfma_f32_16x16x32_f16(aM0, bg0, zC, 0, 0, 0);
      Ga = __builtin_amdgcn_mfma_f32_16x16x32_f16(aM1, bg1, Ga, 0, 0, 0);
      Gg0[t] = Ga[0] + Sb0;
      Gg1[t] = Ga[1] + Sb1;

      ax[t] = tabs[(bb + n) * 2 + 0];
      ay[t] = tabs[(bb + n) * 2 + 1];
#pragma unroll
      for (int r = 0; r < 4; ++r) {
        const int b = bb + 4 * q + r;
        cst[t][r] = c0[b * 64 + hs + n];
        hbuf[t * 1152 + (4 * q + r) * 72 + hs + n] =
            (_Float16)h0[b * 64 + hs + n];
      }
      xf[t] = build_x(trel[(bb + n) * 2 + 0], trel[(bb + n) * 2 + 1]);
    }
  }

  const int ro = n * 72 + q * 8;
  const int wo = (4 * q) * 72 + hs + n;
  const float K2 = 2.8853900817779268f;

  int poff = 0;  // dbuf toggle: 0 <-> 2304
  for (int s = 0; s <= SEQL; ++s) {
    __syncthreads();  // hbuf[poff] holds h_s for all 64 hidden units, both tiles
    f16x8 ah0[NT], ah1[NT];
#pragma unroll
    for (int t = 0; t < NT; ++t) {
      ah0[t] = *(const f16x8*)(hbuf + poff + t * 1152 + ro);
      ah1[t] = *(const f16x8*)(hbuf + poff + t * 1152 + ro + 32);
    }

    if (s > 0) {
      // rel_{s-1}: D[p][batch], regs 0,1 valid on every quad -> lane-local.
#pragma unroll
      for (int t = 0; t < NT; ++t) {
        f32x4 p = __builtin_amdgcn_mfma_f32_16x16x32_f16(awp0, ah0[t], zC,
                                                         0, 0, 0);
        p = __builtin_amdgcn_mfma_f32_16x16x32_f16(awp1, ah1[t], p, 0, 0, 0);
        float u0 = p[0] + Gg0[t] + fmaf(ax[t], Sx0, ay[t] * Sy0);
        float u1 = p[1] + Gg1[t] + fmaf(ax[t], Sx1, ay[t] * Sy1);
        ax[t] += u0;
        ay[t] += u1;
        if (w == t && lane < 16) {
          float2 v;
          v.x = u0;
          v.y = u1;
          ((float2*)outp)[(size_t)(s - 1) * B_TOT + bbase + 16 * t + lane] = v;
        }
        xf[t] = build_x(u0, u1);  // u0,u1 lane-local, no shuffle
      }
    }

    if (s < SEQL) {
      f32x4 acc[NT][4];
#pragma unroll
      for (int g = 0; g < 4; ++g)
#pragma unroll
        for (int t = 0; t < NT; ++t) {
          f32x4 a = __builtin_amdgcn_mfma_f32_16x16x32_f16(ah0[t], bw[g][0],
                                                           zC, 0, 0, 0);
          a = __builtin_amdgcn_mfma_f32_16x16x32_f16(ah1[t], bw[g][1], a,
                                                     0, 0, 0);
          a = __builtin_amdgcn_mfma_f32_16x16x32_f16(xf[t], bw[g][2], a,
                                                     0, 0, 0);
          acc[t][g] = a;
        }
#pragma unroll
      for (int t = 0; t < NT; ++t) {
        _Float16* hw = hbuf + (poff ^ 2304) + t * 1152 + wo;
        // accs prescaled: acc0=-i*log2e, acc1=-f*log2e, acc2=2g*log2e,
        // acc3=-o*log2e. Pairwise f32x2 so non-trans ALU goes v_pk_*_f32.
#pragma unroll
        for (int pr = 0; pr < 2; ++pr) {
          const int ra = 2 * pr, rb = 2 * pr + 1;
          f32x2 Av = {fexp2(acc[t][0][ra]), fexp2(acc[t][0][rb])};
          f32x2 Fv = {fexp2(acc[t][1][ra]), fexp2(acc[t][1][rb])};
          f32x2 Bv = {fexp2(acc[t][2][ra]), fexp2(acc[t][2][rb])};
          const f32x2 one = {1.f, 1.f};
          f32x2 t1 = Av + one;
          f32x2 t2 = Bv + one;
          f32x2 t3 = Fv + one;
          f32x2 t4 = Bv - one;
          f32x2 m1 = t1 * t2;
          f32x2 cs = {cst[t][ra], cst[t][rb]};
          f32x2 num = cs * m1 + t4 * t3;
          f32x2 den = m1 * t3;
          f32x2 cc = {num[0] * frcp(den[0]), num[1] * frcp(den[1])};
          cst[t][ra] = cc[0];
          cst[t][rb] = cc[1];
          f32x2 Cv = {fexp2(acc[t][3][ra]), fexp2(acc[t][3][rb])};
          f32x2 k2c = cc * K2;
          f32x2 Dv = {fexp2(k2c[0]), fexp2(k2c[1])};
          f32x2 hd = (Cv + one) * (Dv + one);
          f32x2 hnm = Dv - one;
          hw[72 * ra] = (_Float16)(hnm[0] * frcp(hd[0]));
          hw[72 * rb] = (_Float16)(hnm[1] * frcp(hd[1]));
        }
      }
      poff ^= 2304;
    }
  }
}

extern "C" void kernel_launch(void* const* d_in, const int* in_sizes, int n_in,
                              void* d_out, int out_size, void* d_ws,
                              size_t ws_size, hipStream_t stream) {
  (void)in_sizes; (void)n_in; (void)out_size; (void)ws_size;
  const float* tabs  = (const float*)d_in[0];
  const float* trel  = (const float*)d_in[1];
  const float* h0    = (const float*)d_in[2];
  const float* c0    = (const float*)d_in[3];
  const float* goals = (const float*)d_in[4];
  const float* Wih   = (const float*)d_in[5];
  const float* Whh   = (const float*)d_in[6];
  const float* bih   = (const float*)d_in[7];
  const float* bhh   = (const float*)d_in[8];
  const float* Wse   = (const float*)d_in[9];
  const float* bse   = (const float*)d_in[10];
  const float* Wh2p  = (const float*)d_in[11];
  const float* bh2p  = (const float*)d_in[12];
  const float* Wgoal = (const float*)d_in[13];
  const float* bgoal = (const float*)d_in[14];
  const float* Wabs  = (const float*)d_in[15];
  const float* babs  = (const float*)d_in[16];
  float* wsf = (float*)d_ws;

  setup_consts<<<dim3(1), dim3(128), 0, stream>>>(Wgoal, bgoal, Wh2p, bh2p,
                                                  Wabs, babs, wsf);
  lstm_mfma<<<dim3(B_TOT / (16 * NT)), dim3(256), 0, stream>>>(
      tabs, trel, h0, c0, goals, Wih, Whh, bih, bhh, Wse, bse, Wh2p, wsf,
      (float*)d_out);
}